// Round 11
// baseline (1006.097 us; speedup 1.0000x reference)
//
#include <hip/hip_runtime.h>
#include <hip/hip_bf16.h>

#define NTOK 8192
#define DIM  1024
#define HID  2816
#define ROWS_CAP 25600   // 8192 shared + 16384 assignments + pad headroom
#define TCAP 200         // 64 shared tiles + max 135 expert tiles

typedef __bf16 bf16x8 __attribute__((ext_vector_type(8)));
typedef float  f32x4  __attribute__((ext_vector_type(4)));

__device__ __forceinline__ unsigned short f2bf(float f) {
  unsigned int x = __float_as_uint(f);
  unsigned int r = (x + 0x7fffu + ((x >> 16) & 1u)) >> 16;
  return (unsigned short)r;
}
__device__ __forceinline__ float gelu_erf(float g) {
  return 0.5f * g * (1.0f + erff(g * 0.70710678118654752f));
}

__device__ __forceinline__ void gload16(const void* g, void* l) {
  __builtin_amdgcn_global_load_lds(
      (__attribute__((address_space(1))) void*)(g),
      (__attribute__((address_space(3))) void*)(l), 16, 0, 0);
}

// XCD-locality swizzle: all column-blocks of one tile land on one XCD.
// lin in [0, nb); requires nb%8==0 for the swizzled path (bijective).
__device__ __forceinline__ int xcd_seq(int lin, int nb) {
  if ((nb & 7) == 0) {
    int per = nb >> 3;
    return (lin & 7) * per + (lin >> 3);
  }
  return lin;
}

// ---------------- merged transposes: out[c][r] = bf16(in[r][c]) ----------------

__global__ __launch_bounds__(256) void k_transpose_DH(
    const float* __restrict__ eg, const float* __restrict__ eu,
    const float* __restrict__ sg, const float* __restrict__ su,
    unsigned short* __restrict__ WgT, unsigned short* __restrict__ WuT,
    unsigned short* __restrict__ SgT, unsigned short* __restrict__ SuT) {
  __shared__ float t[32][33];
  int z = blockIdx.z;
  const float* in; unsigned short* out;
  if (z < 8)        { in = eg + (size_t)z * DIM * HID;       out = WgT + (size_t)z * DIM * HID; }
  else if (z < 16)  { in = eu + (size_t)(z - 8) * DIM * HID; out = WuT + (size_t)(z - 8) * DIM * HID; }
  else if (z == 16) { in = sg; out = SgT; }
  else              { in = su; out = SuT; }
  const int R = DIM, C = HID;
  int c0 = blockIdx.x * 32, r0 = blockIdx.y * 32;
  int tx = threadIdx.x, ty = threadIdx.y;
  #pragma unroll
  for (int i = ty; i < 32; i += 8)
    t[i][tx] = in[(size_t)(r0 + i) * C + c0 + tx];
  __syncthreads();
  #pragma unroll
  for (int i = ty; i < 32; i += 8)
    out[(size_t)(c0 + i) * R + r0 + tx] = f2bf(t[tx][i]);
}

__global__ __launch_bounds__(256) void k_transpose_HD(
    const float* __restrict__ ed, const float* __restrict__ sd,
    unsigned short* __restrict__ WdT, unsigned short* __restrict__ SdT) {
  __shared__ float t[32][33];
  int z = blockIdx.z;
  const float* in; unsigned short* out;
  if (z < 8) { in = ed + (size_t)z * HID * DIM; out = WdT + (size_t)z * HID * DIM; }
  else       { in = sd; out = SdT; }
  const int R = HID, C = DIM;
  int c0 = blockIdx.x * 32, r0 = blockIdx.y * 32;
  int tx = threadIdx.x, ty = threadIdx.y;
  #pragma unroll
  for (int i = ty; i < 32; i += 8)
    t[i][tx] = in[(size_t)(r0 + i) * C + c0 + tx];
  __syncthreads();
  #pragma unroll
  for (int i = ty; i < 32; i += 8)
    out[(size_t)(c0 + i) * R + r0 + tx] = f2bf(t[tx][i]);
}

// ---------------- router + fused x->bf16 cast (block-reduced stats) ----------------

__global__ __launch_bounds__(256) void k_router(const float* __restrict__ x,
                                                const float* __restrict__ gw,
                                                unsigned short* __restrict__ xb,
                                                int* __restrict__ top_idx,
                                                float* __restrict__ top_w,
                                                int* __restrict__ counts,
                                                float* __restrict__ f_cnt,
                                                float* __restrict__ P_sum) {
  __shared__ float s_p[8];
  __shared__ int   s_cnt[8];
  __shared__ int   s_f[8];
  int tid = threadIdx.x;
  if (tid < 8) { s_p[tid] = 0.f; s_cnt[tid] = 0; s_f[tid] = 0; }
  __syncthreads();

  int lane = tid & 63, wv = tid >> 6;
  float ploc[8] = {0,0,0,0,0,0,0,0};
  int   cloc[8] = {0,0,0,0,0,0,0,0};
  int   floc[8] = {0,0,0,0,0,0,0,0};

  for (int t = blockIdx.x * 4 + wv; t < NTOK; t += 1024) {
    const float4* xr = (const float4*)(x + (size_t)t * DIM) + lane * 4;
    float4 v0 = xr[0], v1 = xr[1], v2 = xr[2], v3 = xr[3];
    float xv[16] = {v0.x, v0.y, v0.z, v0.w, v1.x, v1.y, v1.z, v1.w,
                    v2.x, v2.y, v2.z, v2.w, v3.x, v3.y, v3.z, v3.w};
    ushort4* xw = (ushort4*)(xb + (size_t)t * DIM + lane * 16);
    #pragma unroll
    for (int q = 0; q < 4; ++q)
      xw[q] = make_ushort4(f2bf(xv[q * 4]), f2bf(xv[q * 4 + 1]),
                           f2bf(xv[q * 4 + 2]), f2bf(xv[q * 4 + 3]));
    float acc[8] = {0.f,0.f,0.f,0.f,0.f,0.f,0.f,0.f};
    #pragma unroll
    for (int i = 0; i < 16; ++i) {
      const float* g = gw + (size_t)(lane * 16 + i) * 8;
      #pragma unroll
      for (int e = 0; e < 8; ++e) acc[e] += xv[i] * g[e];
    }
    #pragma unroll
    for (int e = 0; e < 8; ++e) {
      #pragma unroll
      for (int off = 32; off > 0; off >>= 1)
        acc[e] += __shfl_xor(acc[e], off, 64);
    }
    if (lane == 0) {
      int i1 = 0; float l1 = acc[0];
      #pragma unroll
      for (int e = 1; e < 8; ++e) if (acc[e] > l1) { l1 = acc[e]; i1 = e; }
      int i2 = -1; float l2 = -3.0e38f;
      #pragma unroll
      for (int e = 0; e < 8; ++e) if (e != i1 && acc[e] > l2) { l2 = acc[e]; i2 = e; }
      float e2 = expf(l2 - l1);
      float inv12 = 1.0f / (1.0f + e2);
      top_idx[2 * t] = i1; top_idx[2 * t + 1] = i2;
      top_w[2 * t] = inv12; top_w[2 * t + 1] = e2 * inv12;
      float s = 0.f, p[8];
      #pragma unroll
      for (int e = 0; e < 8; ++e) { p[e] = expf(acc[e] - l1); s += p[e]; }
      float invs = 1.0f / s;
      #pragma unroll
      for (int e = 0; e < 8; ++e) {
        ploc[e] += p[e] * invs;
        cloc[e] += (e == i1) + (e == i2);
        floc[e] += (e == i1);
      }
    }
  }
  if (lane == 0) {
    #pragma unroll
    for (int e = 0; e < 8; ++e) {
      atomicAdd(&s_p[e], ploc[e]);
      atomicAdd(&s_cnt[e], cloc[e]);
      atomicAdd(&s_f[e], floc[e]);
    }
  }
  __syncthreads();
  if (tid < 8) {
    atomicAdd(&P_sum[tid], s_p[tid]);
    atomicAdd(&counts[tid], s_cnt[tid]);
    atomicAdd(&f_cnt[tid], (float)s_f[tid]);
  }
}

// ---------------- segment setup / scatter ----------------

__global__ __launch_bounds__(256) void k_setup(const int* __restrict__ counts,
                                               int* __restrict__ cursors,
                                               int* __restrict__ tile_expert,
                                               int* __restrict__ tile_row0,
                                               int* __restrict__ perm,
                                               float* __restrict__ wrow) {
  int t = threadIdx.x;
  for (int r = t; r < ROWS_CAP; r += 256) {
    perm[r] = (r < NTOK) ? r : 0;
    wrow[r] = (r < NTOK) ? 1.0f : 0.0f;
  }
  if (t == 0) {
    int so[8], pe[8];
    int cur = NTOK;
    for (int e = 0; e < 8; ++e) {
      so[e] = cur;
      pe[e] = ((counts[e] + 127) >> 7) << 7;
      cur += pe[e];
    }
    for (int e = 0; e < 8; ++e) cursors[e] = so[e];
    for (int tile = 0; tile < TCAP; ++tile) {
      int r0 = tile << 7;
      int ex;
      if (tile < NTOK / 128) ex = 8;            // shared expert
      else if (r0 < cur) {
        ex = 0;
        for (int e = 0; e < 8; ++e) if (r0 >= so[e] && r0 < so[e] + pe[e]) ex = e;
      } else ex = -1;
      tile_expert[tile] = ex;
      tile_row0[tile] = r0;
    }
  }
}

__global__ __launch_bounds__(256) void k_scatter(const int* __restrict__ top_idx,
                                                 const float* __restrict__ top_w,
                                                 int* __restrict__ cursors,
                                                 int* __restrict__ perm,
                                                 float* __restrict__ wrow) {
  int i = blockIdx.x * 256 + threadIdx.x;
  if (i < NTOK * 2) {
    int e = top_idx[i];
    float w = top_w[i];
    int slot = atomicAdd(&cursors[e], 1);
    perm[slot] = i >> 1;
    wrow[slot] = w;
  }
}

// ---------------- stage A: h = gelu(x@gate) * (x@up), gathered rows ----------------
// 1D grid, XCD-swizzled so a tile's 44 column-blocks share one XCD's L2.

__global__ __launch_bounds__(256) void k_stageA(const unsigned short* __restrict__ xb,
    const unsigned short* __restrict__ WgT, const unsigned short* __restrict__ WuT,
    const unsigned short* __restrict__ SgT, const unsigned short* __restrict__ SuT,
    const int* __restrict__ perm,
    const int* __restrict__ tile_expert, const int* __restrict__ tile_row0,
    unsigned short* __restrict__ h, int t0, int row_base, int nblocks) {
  int s = xcd_seq(blockIdx.x, nblocks);
  int tile = t0 + s / (HID / 64);
  int h0 = (s % (HID / 64)) * 64;
  int e = tile_expert[tile];
  if (e < 0) return;
  const unsigned short* Bg = (e < 8) ? WgT + (size_t)e * HID * DIM : SgT;
  const unsigned short* Bu = (e < 8) ? WuT + (size_t)e * HID * DIM : SuT;
  int rows0 = tile_row0[tile];

  __shared__ unsigned short As[128 * 64];
  __shared__ unsigned short Bgs[64 * 64];
  __shared__ unsigned short Bus[64 * 64];

  int tid = threadIdx.x, lane = tid & 63, wv = tid >> 6;
  int wr = wv >> 1, wc = wv & 1;
  int rlo = lane >> 3;
  int koff = (((lane & 7) ^ rlo) * 8);       // pre-swizzled source column
  int rsw = (lane & 7) << 4;                 // read-side XOR (row&7)<<4

  int prow[4];
  #pragma unroll
  for (int i = 0; i < 4; ++i) prow[i] = perm[rows0 + i * 32 + wv * 8 + rlo];
  int bn[2];
  #pragma unroll
  for (int i = 0; i < 2; ++i) bn[i] = h0 + i * 32 + wv * 8 + rlo;

  f32x4 accg[4][2] = {};
  f32x4 accu[4][2] = {};

  for (int kb = 0; kb < DIM / 64; ++kb) {
    int k0 = kb * 64;
    #pragma unroll
    for (int i = 0; i < 4; ++i)
      gload16(xb + (size_t)prow[i] * DIM + k0 + koff, (char*)As + (i * 32 + wv * 8) * 128);
    #pragma unroll
    for (int i = 0; i < 2; ++i) {
      gload16(Bg + (size_t)bn[i] * DIM + k0 + koff, (char*)Bgs + (i * 32 + wv * 8) * 128);
      gload16(Bu + (size_t)bn[i] * DIM + k0 + koff, (char*)Bus + (i * 32 + wv * 8) * 128);
    }
    __syncthreads();
    #pragma unroll
    for (int kk = 0; kk < 2; ++kk) {
      int kbyte = (kk * 64 + (lane >> 4) * 16) ^ rsw;
      bf16x8 a[4], bg[2], bu[2];
      #pragma unroll
      for (int mi = 0; mi < 4; ++mi)
        a[mi] = *(const bf16x8*)((const char*)As + (wr * 64 + mi * 16 + (lane & 15)) * 128 + kbyte);
      #pragma unroll
      for (int ni = 0; ni < 2; ++ni) {
        bg[ni] = *(const bf16x8*)((const char*)Bgs + (wc * 32 + ni * 16 + (lane & 15)) * 128 + kbyte);
        bu[ni] = *(const bf16x8*)((const char*)Bus + (wc * 32 + ni * 16 + (lane & 15)) * 128 + kbyte);
      }
      #pragma unroll
      for (int mi = 0; mi < 4; ++mi) {
        #pragma unroll
        for (int ni = 0; ni < 2; ++ni) {
          accg[mi][ni] = __builtin_amdgcn_mfma_f32_16x16x32_bf16(a[mi], bg[ni], accg[mi][ni], 0, 0, 0);
          accu[mi][ni] = __builtin_amdgcn_mfma_f32_16x16x32_bf16(a[mi], bu[ni], accu[mi][ni], 0, 0, 0);
        }
      }
    }
    __syncthreads();
  }
  #pragma unroll
  for (int mi = 0; mi < 4; ++mi) {
    #pragma unroll
    for (int ni = 0; ni < 2; ++ni) {
      #pragma unroll
      for (int j = 0; j < 4; ++j) {
        int rg = rows0 - row_base + wr * 64 + mi * 16 + (lane >> 4) * 4 + j;
        int cg = h0 + wc * 32 + ni * 16 + (lane & 15);
        float g = accg[mi][ni][j];
        float u = accu[mi][ni][j];
        h[(size_t)rg * HID + cg] = f2bf(gelu_erf(g) * u);
      }
    }
  }
}

// ---------------- stage B: out(f32) = / += w * (h @ downT) ----------------

template <bool STORE>
__global__ __launch_bounds__(256) void k_stageB(const unsigned short* __restrict__ h,
    const unsigned short* __restrict__ WdT, const unsigned short* __restrict__ SdT,
    const int* __restrict__ perm, const float* __restrict__ wrow,
    const int* __restrict__ tile_expert, const int* __restrict__ tile_row0,
    float* __restrict__ out, int t0, int row_base, int nblocks) {
  int s = xcd_seq(blockIdx.x, nblocks);
  int tile = t0 + s / (DIM / 128);
  int n0 = (s % (DIM / 128)) * 128;
  int e = tile_expert[tile];
  if (e < 0) return;
  const unsigned short* Bd = (e < 8) ? WdT + (size_t)e * DIM * HID : SdT;
  int rows0 = tile_row0[tile];

  __shared__ unsigned short As[128 * 64];
  __shared__ unsigned short Bs[128 * 64];

  int tid = threadIdx.x, lane = tid & 63, wv = tid >> 6;
  int wr = wv >> 1, wc = wv & 1;
  int rlo = lane >> 3;
  int koff = (((lane & 7) ^ rlo) * 8);
  int rsw = (lane & 7) << 4;

  f32x4 acc[4][4] = {};

  for (int kb = 0; kb < HID / 64; ++kb) {
    int k0 = kb * 64;
    #pragma unroll
    for (int i = 0; i < 4; ++i) {
      int rb = i * 32 + wv * 8;
      int r = rb + rlo;
      gload16(h + (size_t)(rows0 - row_base + r) * HID + k0 + koff, (char*)As + rb * 128);
      gload16(Bd + (size_t)(n0 + r) * HID + k0 + koff, (char*)Bs + rb * 128);
    }
    __syncthreads();
    #pragma unroll
    for (int kk = 0; kk < 2; ++kk) {
      int kbyte = (kk * 64 + (lane >> 4) * 16) ^ rsw;
      bf16x8 a[4], b[4];
      #pragma unroll
      for (int mi = 0; mi < 4; ++mi)
        a[mi] = *(const bf16x8*)((const char*)As + (wr * 64 + mi * 16 + (lane & 15)) * 128 + kbyte);
      #pragma unroll
      for (int ni = 0; ni < 4; ++ni)
        b[ni] = *(const bf16x8*)((const char*)Bs + (wc * 64 + ni * 16 + (lane & 15)) * 128 + kbyte);
      #pragma unroll
      for (int mi = 0; mi < 4; ++mi) {
        #pragma unroll
        for (int ni = 0; ni < 4; ++ni)
          acc[mi][ni] = __builtin_amdgcn_mfma_f32_16x16x32_bf16(a[mi], b[ni], acc[mi][ni], 0, 0, 0);
      }
    }
    __syncthreads();
  }
  #pragma unroll
  for (int mi = 0; mi < 4; ++mi) {
    #pragma unroll
    for (int j = 0; j < 4; ++j) {
      int rl = wr * 64 + mi * 16 + (lane >> 4) * 4 + j;
      int token = perm[rows0 + rl];
      float w = wrow[rows0 + rl];
      #pragma unroll
      for (int ni = 0; ni < 4; ++ni) {
        int col = n0 + wc * 64 + ni * 16 + (lane & 15);
        if (STORE) out[(size_t)token * DIM + col] = w * acc[mi][ni][j];
        else atomicAdd(&out[(size_t)token * DIM + col], w * acc[mi][ni][j]);
      }
    }
  }
}

// ---------------- aux loss (f32) ----------------

__global__ void k_aux(const float* __restrict__ f_cnt, const float* __restrict__ P_sum,
                      float* __restrict__ aux_out) {
  if (threadIdx.x == 0 && blockIdx.x == 0) {
    float a = 0.f;
    #pragma unroll
    for (int e = 0; e < 8; ++e) a += f_cnt[e] * P_sum[e];
    a *= 0.01f * 8.f / ((float)NTOK * (float)NTOK);
    aux_out[0] = a;
  }
}

// ---------------- launch ----------------

extern "C" void kernel_launch(void* const* d_in, const int* in_sizes, int n_in,
                              void* d_out, int out_size, void* d_ws, size_t ws_size,
                              hipStream_t stream) {
  const float* x  = (const float*)d_in[0];
  const float* gw = (const float*)d_in[1];
  const float* eg = (const float*)d_in[2];
  const float* eu = (const float*)d_in[3];
  const float* ed = (const float*)d_in[4];
  const float* sg = (const float*)d_in[5];
  const float* su = (const float*)d_in[6];
  const float* sd = (const float*)d_in[7];
  float* out = (float*)d_out;

  char* ws = (char*)d_ws;
  size_t off = 0;
  auto take = [&](size_t sz) { size_t o = off; off += (sz + 255) & ~(size_t)255; return o; };
  const size_t OFF_XB   = take((size_t)NTOK * DIM * 2);
  const size_t OFF_WGT  = take((size_t)8 * HID * DIM * 2);
  const size_t OFF_WUT  = take((size_t)8 * HID * DIM * 2);
  const size_t OFF_WDT  = take((size_t)8 * HID * DIM * 2);
  const size_t OFF_SGT  = take((size_t)HID * DIM * 2);
  const size_t OFF_SUT  = take((size_t)HID * DIM * 2);
  const size_t OFF_SDT  = take((size_t)HID * DIM * 2);
  const size_t OFF_TI   = take((size_t)NTOK * 2 * 4);
  const size_t OFF_TW   = take((size_t)NTOK * 2 * 4);
  const size_t OFF_PERM = take((size_t)ROWS_CAP * 4);
  const size_t OFF_WROW = take((size_t)ROWS_CAP * 4);
  const size_t OFF_STATS= take(256);
  const size_t OFF_CURS = take(256);
  const size_t OFF_TE   = take(TCAP * 4);
  const size_t OFF_TR   = take(TCAP * 4);
  const size_t OFF_H    = off;   // h-buffer takes ALL remaining space

  const size_t TILE_H_BYTES = (size_t)128 * HID * 2;
  size_t avail = (ws_size > OFF_H) ? (ws_size - OFF_H) : 0;
  int G = (int)((avail / TILE_H_BYTES < (size_t)TCAP) ? (avail / TILE_H_BYTES) : (size_t)TCAP);
  if (G < 1) return;

  unsigned short* xb  = (unsigned short*)(ws + OFF_XB);
  unsigned short* WgT = (unsigned short*)(ws + OFF_WGT);
  unsigned short* WuT = (unsigned short*)(ws + OFF_WUT);
  unsigned short* WdT = (unsigned short*)(ws + OFF_WDT);
  unsigned short* SgT = (unsigned short*)(ws + OFF_SGT);
  unsigned short* SuT = (unsigned short*)(ws + OFF_SUT);
  unsigned short* SdT = (unsigned short*)(ws + OFF_SDT);
  int* top_idx        = (int*)(ws + OFF_TI);
  float* top_w        = (float*)(ws + OFF_TW);
  int* perm           = (int*)(ws + OFF_PERM);
  float* wrow         = (float*)(ws + OFF_WROW);
  int* counts         = (int*)(ws + OFF_STATS);
  float* f_cnt        = (float*)(ws + OFF_STATS + 32);
  float* P_sum        = (float*)(ws + OFF_STATS + 64);
  int* cursors        = (int*)(ws + OFF_CURS);
  int* tile_expert    = (int*)(ws + OFF_TE);
  int* tile_row0      = (int*)(ws + OFF_TR);
  unsigned short* hbuf = (unsigned short*)(ws + OFF_H);

  hipMemsetAsync(ws + OFF_STATS, 0, 256, stream);

  k_transpose_DH<<<dim3(HID / 32, DIM / 32, 18), dim3(32, 8), 0, stream>>>(
      eg, eu, sg, su, WgT, WuT, SgT, SuT);
  k_transpose_HD<<<dim3(DIM / 32, HID / 32, 9), dim3(32, 8), 0, stream>>>(
      ed, sd, WdT, SdT);

  k_router<<<256, 256, 0, stream>>>(x, gw, xb, top_idx, top_w, counts, f_cnt, P_sum);
  k_setup<<<1, 256, 0, stream>>>(counts, cursors, tile_expert, tile_row0, perm, wrow);
  k_scatter<<<NTOK * 2 / 256, 256, 0, stream>>>(top_idx, top_w, cursors, perm, wrow);

  for (int t0 = 0; t0 < TCAP; t0 += G) {
    int nt = (TCAP - t0 < G) ? (TCAP - t0) : G;
    int row_base = t0 * 128;
    int nbA = (HID / 64) * nt;
    k_stageA<<<nbA, 256, 0, stream>>>(xb, WgT, WuT, SgT, SuT, perm,
                                      tile_expert, tile_row0, hbuf, t0, row_base, nbA);
    int ns = 0;
    if (t0 < 64) { ns = 64 - t0; if (ns > nt) ns = nt; }
    int ne = nt - ns;
    if (ns > 0) {
      int nbS = (DIM / 128) * ns;
      k_stageB<true><<<nbS, 256, 0, stream>>>(hbuf, WdT, SdT, perm, wrow,
                                              tile_expert, tile_row0, out, t0, row_base, nbS);
    }
    if (ne > 0) {
      int nbE = (DIM / 128) * ne;
      k_stageB<false><<<nbE, 256, 0, stream>>>(hbuf, WdT, SdT, perm, wrow,
                                               tile_expert, tile_row0, out, t0 + ns, row_base, nbE);
    }
  }

  k_aux<<<1, 64, 0, stream>>>(f_cnt, P_sum, out + (size_t)NTOK * DIM);
}

// Round 12
// 966.423 us; speedup vs baseline: 1.0411x; 1.0411x over previous
//
#include <hip/hip_runtime.h>
#include <hip/hip_bf16.h>

#define NTOK 8192
#define DIM  1024
#define HID  2816
#define ROWS_CAP 25600   // 8192 shared + 16384 assignments + pad headroom
#define TCAP 200         // 64 shared tiles + max 135 expert tiles

typedef __bf16 bf16x8 __attribute__((ext_vector_type(8)));
typedef float  f32x4  __attribute__((ext_vector_type(4)));

__device__ __forceinline__ unsigned short f2bf(float f) {
  unsigned int x = __float_as_uint(f);
  unsigned int r = (x + 0x7fffu + ((x >> 16) & 1u)) >> 16;
  return (unsigned short)r;
}
__device__ __forceinline__ float gelu_erf(float g) {
  return 0.5f * g * (1.0f + erff(g * 0.70710678118654752f));
}

__device__ __forceinline__ void gload16(const void* g, void* l) {
  __builtin_amdgcn_global_load_lds(
      (__attribute__((address_space(1))) void*)(g),
      (__attribute__((address_space(3))) void*)(l), 16, 0, 0);
}

// ---------------- merged transposes: out[c][r] = bf16(in[r][c]) ----------------

__global__ __launch_bounds__(256) void k_transpose_DH(
    const float* __restrict__ eg, const float* __restrict__ eu,
    const float* __restrict__ sg, const float* __restrict__ su,
    unsigned short* __restrict__ WgT, unsigned short* __restrict__ WuT,
    unsigned short* __restrict__ SgT, unsigned short* __restrict__ SuT) {
  __shared__ float t[32][33];
  int z = blockIdx.z;
  const float* in; unsigned short* out;
  if (z < 8)        { in = eg + (size_t)z * DIM * HID;       out = WgT + (size_t)z * DIM * HID; }
  else if (z < 16)  { in = eu + (size_t)(z - 8) * DIM * HID; out = WuT + (size_t)(z - 8) * DIM * HID; }
  else if (z == 16) { in = sg; out = SgT; }
  else              { in = su; out = SuT; }
  const int R = DIM, C = HID;
  int c0 = blockIdx.x * 32, r0 = blockIdx.y * 32;
  int tx = threadIdx.x, ty = threadIdx.y;
  #pragma unroll
  for (int i = ty; i < 32; i += 8)
    t[i][tx] = in[(size_t)(r0 + i) * C + c0 + tx];
  __syncthreads();
  #pragma unroll
  for (int i = ty; i < 32; i += 8)
    out[(size_t)(c0 + i) * R + r0 + tx] = f2bf(t[tx][i]);
}

__global__ __launch_bounds__(256) void k_transpose_HD(
    const float* __restrict__ ed, const float* __restrict__ sd,
    unsigned short* __restrict__ WdT, unsigned short* __restrict__ SdT) {
  __shared__ float t[32][33];
  int z = blockIdx.z;
  const float* in; unsigned short* out;
  if (z < 8) { in = ed + (size_t)z * HID * DIM; out = WdT + (size_t)z * HID * DIM; }
  else       { in = sd; out = SdT; }
  const int R = HID, C = DIM;
  int c0 = blockIdx.x * 32, r0 = blockIdx.y * 32;
  int tx = threadIdx.x, ty = threadIdx.y;
  #pragma unroll
  for (int i = ty; i < 32; i += 8)
    t[i][tx] = in[(size_t)(r0 + i) * C + c0 + tx];
  __syncthreads();
  #pragma unroll
  for (int i = ty; i < 32; i += 8)
    out[(size_t)(c0 + i) * R + r0 + tx] = f2bf(t[tx][i]);
}

// ---------------- router + fused x->bf16 cast (block-reduced stats) ----------------

__global__ __launch_bounds__(256) void k_router(const float* __restrict__ x,
                                                const float* __restrict__ gw,
                                                unsigned short* __restrict__ xb,
                                                int* __restrict__ top_idx,
                                                float* __restrict__ top_w,
                                                int* __restrict__ counts,
                                                float* __restrict__ f_cnt,
                                                float* __restrict__ P_sum) {
  __shared__ float s_p[8];
  __shared__ int   s_cnt[8];
  __shared__ int   s_f[8];
  int tid = threadIdx.x;
  if (tid < 8) { s_p[tid] = 0.f; s_cnt[tid] = 0; s_f[tid] = 0; }
  __syncthreads();

  int lane = tid & 63, wv = tid >> 6;
  float ploc[8] = {0,0,0,0,0,0,0,0};
  int   cloc[8] = {0,0,0,0,0,0,0,0};
  int   floc[8] = {0,0,0,0,0,0,0,0};

  for (int t = blockIdx.x * 4 + wv; t < NTOK; t += 1024) {
    const float4* xr = (const float4*)(x + (size_t)t * DIM) + lane * 4;
    float4 v0 = xr[0], v1 = xr[1], v2 = xr[2], v3 = xr[3];
    float xv[16] = {v0.x, v0.y, v0.z, v0.w, v1.x, v1.y, v1.z, v1.w,
                    v2.x, v2.y, v2.z, v2.w, v3.x, v3.y, v3.z, v3.w};
    ushort4* xw = (ushort4*)(xb + (size_t)t * DIM + lane * 16);
    #pragma unroll
    for (int q = 0; q < 4; ++q)
      xw[q] = make_ushort4(f2bf(xv[q * 4]), f2bf(xv[q * 4 + 1]),
                           f2bf(xv[q * 4 + 2]), f2bf(xv[q * 4 + 3]));
    float acc[8] = {0.f,0.f,0.f,0.f,0.f,0.f,0.f,0.f};
    #pragma unroll
    for (int i = 0; i < 16; ++i) {
      const float* g = gw + (size_t)(lane * 16 + i) * 8;
      #pragma unroll
      for (int e = 0; e < 8; ++e) acc[e] += xv[i] * g[e];
    }
    #pragma unroll
    for (int e = 0; e < 8; ++e) {
      #pragma unroll
      for (int off = 32; off > 0; off >>= 1)
        acc[e] += __shfl_xor(acc[e], off, 64);
    }
    if (lane == 0) {
      int i1 = 0; float l1 = acc[0];
      #pragma unroll
      for (int e = 1; e < 8; ++e) if (acc[e] > l1) { l1 = acc[e]; i1 = e; }
      int i2 = -1; float l2 = -3.0e38f;
      #pragma unroll
      for (int e = 0; e < 8; ++e) if (e != i1 && acc[e] > l2) { l2 = acc[e]; i2 = e; }
      float e2 = expf(l2 - l1);
      float inv12 = 1.0f / (1.0f + e2);
      top_idx[2 * t] = i1; top_idx[2 * t + 1] = i2;
      top_w[2 * t] = inv12; top_w[2 * t + 1] = e2 * inv12;
      float s = 0.f, p[8];
      #pragma unroll
      for (int e = 0; e < 8; ++e) { p[e] = expf(acc[e] - l1); s += p[e]; }
      float invs = 1.0f / s;
      #pragma unroll
      for (int e = 0; e < 8; ++e) {
        ploc[e] += p[e] * invs;
        cloc[e] += (e == i1) + (e == i2);
        floc[e] += (e == i1);
      }
    }
  }
  if (lane == 0) {
    #pragma unroll
    for (int e = 0; e < 8; ++e) {
      atomicAdd(&s_p[e], ploc[e]);
      atomicAdd(&s_cnt[e], cloc[e]);
      atomicAdd(&s_f[e], floc[e]);
    }
  }
  __syncthreads();
  if (tid < 8) {
    atomicAdd(&P_sum[tid], s_p[tid]);
    atomicAdd(&counts[tid], s_cnt[tid]);
    atomicAdd(&f_cnt[tid], (float)s_f[tid]);
  }
}

// ---------------- segment setup / scatter ----------------

__global__ __launch_bounds__(256) void k_setup(const int* __restrict__ counts,
                                               int* __restrict__ cursors,
                                               int* __restrict__ tile_expert,
                                               int* __restrict__ tile_row0,
                                               int* __restrict__ perm,
                                               float* __restrict__ wrow) {
  int t = threadIdx.x;
  for (int r = t; r < ROWS_CAP; r += 256) {
    perm[r] = (r < NTOK) ? r : 0;
    wrow[r] = (r < NTOK) ? 1.0f : 0.0f;
  }
  if (t == 0) {
    int so[8], pe[8];
    int cur = NTOK;
    for (int e = 0; e < 8; ++e) {
      so[e] = cur;
      pe[e] = ((counts[e] + 127) >> 7) << 7;
      cur += pe[e];
    }
    for (int e = 0; e < 8; ++e) cursors[e] = so[e];
    for (int tile = 0; tile < TCAP; ++tile) {
      int r0 = tile << 7;
      int ex;
      if (tile < NTOK / 128) ex = 8;            // shared expert
      else if (r0 < cur) {
        ex = 0;
        for (int e = 0; e < 8; ++e) if (r0 >= so[e] && r0 < so[e] + pe[e]) ex = e;
      } else ex = -1;
      tile_expert[tile] = ex;
      tile_row0[tile] = r0;
    }
  }
}

__global__ __launch_bounds__(256) void k_scatter(const int* __restrict__ top_idx,
                                                 const float* __restrict__ top_w,
                                                 int* __restrict__ cursors,
                                                 int* __restrict__ perm,
                                                 float* __restrict__ wrow) {
  int i = blockIdx.x * 256 + threadIdx.x;
  if (i < NTOK * 2) {
    int e = top_idx[i];
    float w = top_w[i];
    int slot = atomicAdd(&cursors[e], 1);
    perm[slot] = i >> 1;
    wrow[slot] = w;
  }
}

// ---------------- stage A: h = gelu(x@gate) * (x@up) -------------------------
// dbuf LDS + COUNTED vmcnt(6): previous tile's loads awaited, current tile's
// 6 loads stay in flight across the whole compute phase (T4, m218).

__global__ __launch_bounds__(256) void k_stageA(const unsigned short* __restrict__ xb,
    const unsigned short* __restrict__ WgT, const unsigned short* __restrict__ WuT,
    const unsigned short* __restrict__ SgT, const unsigned short* __restrict__ SuT,
    const int* __restrict__ perm,
    const int* __restrict__ tile_expert, const int* __restrict__ tile_row0,
    unsigned short* __restrict__ h, int t0, int row_base) {
  int tile = t0 + blockIdx.y;
  int e = tile_expert[tile];
  if (e < 0) return;
  const unsigned short* Bg = (e < 8) ? WgT + (size_t)e * HID * DIM : SgT;
  const unsigned short* Bu = (e < 8) ? WuT + (size_t)e * HID * DIM : SuT;
  int rows0 = tile_row0[tile];
  int h0 = blockIdx.x * 64;

  __shared__ unsigned short As[2][128 * 64];
  __shared__ unsigned short Bgs[2][64 * 64];
  __shared__ unsigned short Bus[2][64 * 64];

  int tid = threadIdx.x, lane = tid & 63, wv = tid >> 6;
  int wr = wv >> 1, wc = wv & 1;
  int rlo = lane >> 3;
  int koff = (((lane & 7) ^ rlo) * 8);       // pre-swizzled source column
  int rsw = (lane & 7) << 4;                 // read-side XOR (row&7)<<4

  int prow[4];
  #pragma unroll
  for (int i = 0; i < 4; ++i) prow[i] = perm[rows0 + i * 32 + wv * 8 + rlo];
  int bn[2];
  #pragma unroll
  for (int i = 0; i < 2; ++i) bn[i] = h0 + i * 32 + wv * 8 + rlo;

  f32x4 accg[4][2] = {};
  f32x4 accu[4][2] = {};

  auto stage = [&](int b, int k0) {
    #pragma unroll
    for (int i = 0; i < 4; ++i)
      gload16(xb + (size_t)prow[i] * DIM + k0 + koff, (char*)As[b] + (i * 32 + wv * 8) * 128);
    #pragma unroll
    for (int i = 0; i < 2; ++i) {
      gload16(Bg + (size_t)bn[i] * DIM + k0 + koff, (char*)Bgs[b] + (i * 32 + wv * 8) * 128);
      gload16(Bu + (size_t)bn[i] * DIM + k0 + koff, (char*)Bus[b] + (i * 32 + wv * 8) * 128);
    }
  };

  auto compute = [&](int b) {
    #pragma unroll
    for (int kk = 0; kk < 2; ++kk) {
      int kbyte = (kk * 64 + (lane >> 4) * 16) ^ rsw;
      bf16x8 a[4], bg[2], bu[2];
      #pragma unroll
      for (int mi = 0; mi < 4; ++mi)
        a[mi] = *(const bf16x8*)((const char*)As[b] + (wr * 64 + mi * 16 + (lane & 15)) * 128 + kbyte);
      #pragma unroll
      for (int ni = 0; ni < 2; ++ni) {
        bg[ni] = *(const bf16x8*)((const char*)Bgs[b] + (wc * 32 + ni * 16 + (lane & 15)) * 128 + kbyte);
        bu[ni] = *(const bf16x8*)((const char*)Bus[b] + (wc * 32 + ni * 16 + (lane & 15)) * 128 + kbyte);
      }
      #pragma unroll
      for (int mi = 0; mi < 4; ++mi) {
        #pragma unroll
        for (int ni = 0; ni < 2; ++ni) {
          accg[mi][ni] = __builtin_amdgcn_mfma_f32_16x16x32_bf16(a[mi], bg[ni], accg[mi][ni], 0, 0, 0);
          accu[mi][ni] = __builtin_amdgcn_mfma_f32_16x16x32_bf16(a[mi], bu[ni], accu[mi][ni], 0, 0, 0);
        }
      }
    }
  };

  stage(0, 0);
  int cur = 0;
  for (int kb = 0; kb < DIM / 64 - 1; ++kb) {
    stage(cur ^ 1, (kb + 1) * 64);
    __builtin_amdgcn_sched_barrier(0);
    asm volatile("s_waitcnt vmcnt(6)" ::: "memory");   // oldest 6 (buf[cur]) done
    __builtin_amdgcn_s_barrier();
    __builtin_amdgcn_sched_barrier(0);
    __builtin_amdgcn_s_setprio(1);
    compute(cur);
    __builtin_amdgcn_s_setprio(0);
    __builtin_amdgcn_s_barrier();                      // WAR: reads done before next overwrite
    cur ^= 1;
  }
  asm volatile("s_waitcnt vmcnt(0)" ::: "memory");
  __builtin_amdgcn_s_barrier();
  __builtin_amdgcn_sched_barrier(0);
  compute(cur);

  #pragma unroll
  for (int mi = 0; mi < 4; ++mi) {
    #pragma unroll
    for (int ni = 0; ni < 2; ++ni) {
      #pragma unroll
      for (int j = 0; j < 4; ++j) {
        int rg = rows0 - row_base + wr * 64 + mi * 16 + (lane >> 4) * 4 + j;
        int cg = h0 + wc * 32 + ni * 16 + (lane & 15);
        float g = accg[mi][ni][j];
        float u = accu[mi][ni][j];
        h[(size_t)rg * HID + cg] = f2bf(gelu_erf(g) * u);
      }
    }
  }
}

// ---------------- stage B: out(f32) = / += w * (h @ downT) ----------------

template <bool STORE>
__global__ __launch_bounds__(256) void k_stageB(const unsigned short* __restrict__ h,
    const unsigned short* __restrict__ WdT, const unsigned short* __restrict__ SdT,
    const int* __restrict__ perm, const float* __restrict__ wrow,
    const int* __restrict__ tile_expert, const int* __restrict__ tile_row0,
    float* __restrict__ out, int t0, int row_base) {
  int tile = t0 + blockIdx.y;
  int e = tile_expert[tile];
  if (e < 0) return;
  const unsigned short* Bd = (e < 8) ? WdT + (size_t)e * DIM * HID : SdT;
  int rows0 = tile_row0[tile];
  int n0 = blockIdx.x * 128;

  __shared__ unsigned short As[2][128 * 64];
  __shared__ unsigned short Bs[2][128 * 64];

  int tid = threadIdx.x, lane = tid & 63, wv = tid >> 6;
  int wr = wv >> 1, wc = wv & 1;
  int rlo = lane >> 3;
  int koff = (((lane & 7) ^ rlo) * 8);
  int rsw = (lane & 7) << 4;

  f32x4 acc[4][4] = {};

  auto stage = [&](int b, int k0) {
    #pragma unroll
    for (int i = 0; i < 4; ++i) {
      int rb = i * 32 + wv * 8;
      int r = rb + rlo;
      gload16(h + (size_t)(rows0 - row_base + r) * HID + k0 + koff, (char*)As[b] + rb * 128);
      gload16(Bd + (size_t)(n0 + r) * HID + k0 + koff, (char*)Bs[b] + rb * 128);
    }
  };

  auto compute = [&](int b) {
    #pragma unroll
    for (int kk = 0; kk < 2; ++kk) {
      int kbyte = (kk * 64 + (lane >> 4) * 16) ^ rsw;
      bf16x8 a[4], bb[4];
      #pragma unroll
      for (int mi = 0; mi < 4; ++mi)
        a[mi] = *(const bf16x8*)((const char*)As[b] + (wr * 64 + mi * 16 + (lane & 15)) * 128 + kbyte);
      #pragma unroll
      for (int ni = 0; ni < 4; ++ni)
        bb[ni] = *(const bf16x8*)((const char*)Bs[b] + (wc * 64 + ni * 16 + (lane & 15)) * 128 + kbyte);
      #pragma unroll
      for (int mi = 0; mi < 4; ++mi) {
        #pragma unroll
        for (int ni = 0; ni < 4; ++ni)
          acc[mi][ni] = __builtin_amdgcn_mfma_f32_16x16x32_bf16(a[mi], bb[ni], acc[mi][ni], 0, 0, 0);
      }
    }
  };

  stage(0, 0);
  int cur = 0;
  for (int kb = 0; kb < HID / 64 - 1; ++kb) {
    stage(cur ^ 1, (kb + 1) * 64);
    __builtin_amdgcn_sched_barrier(0);
    asm volatile("s_waitcnt vmcnt(8)" ::: "memory");   // oldest 8 (buf[cur]) done
    __builtin_amdgcn_s_barrier();
    __builtin_amdgcn_sched_barrier(0);
    __builtin_amdgcn_s_setprio(1);
    compute(cur);
    __builtin_amdgcn_s_setprio(0);
    __builtin_amdgcn_s_barrier();
    cur ^= 1;
  }
  asm volatile("s_waitcnt vmcnt(0)" ::: "memory");
  __builtin_amdgcn_s_barrier();
  __builtin_amdgcn_sched_barrier(0);
  compute(cur);

  #pragma unroll
  for (int mi = 0; mi < 4; ++mi) {
    #pragma unroll
    for (int j = 0; j < 4; ++j) {
      int rl = wr * 64 + mi * 16 + (lane >> 4) * 4 + j;
      int token = perm[rows0 + rl];
      float w = wrow[rows0 + rl];
      #pragma unroll
      for (int ni = 0; ni < 4; ++ni) {
        int col = n0 + wc * 64 + ni * 16 + (lane & 15);
        if (STORE) out[(size_t)token * DIM + col] = w * acc[mi][ni][j];
        else atomicAdd(&out[(size_t)token * DIM + col], w * acc[mi][ni][j]);
      }
    }
  }
}

// ---------------- aux loss (f32) ----------------

__global__ void k_aux(const float* __restrict__ f_cnt, const float* __restrict__ P_sum,
                      float* __restrict__ aux_out) {
  if (threadIdx.x == 0 && blockIdx.x == 0) {
    float a = 0.f;
    #pragma unroll
    for (int e = 0; e < 8; ++e) a += f_cnt[e] * P_sum[e];
    a *= 0.01f * 8.f / ((float)NTOK * (float)NTOK);
    aux_out[0] = a;
  }
}

// ---------------- launch ----------------

extern "C" void kernel_launch(void* const* d_in, const int* in_sizes, int n_in,
                              void* d_out, int out_size, void* d_ws, size_t ws_size,
                              hipStream_t stream) {
  const float* x  = (const float*)d_in[0];
  const float* gw = (const float*)d_in[1];
  const float* eg = (const float*)d_in[2];
  const float* eu = (const float*)d_in[3];
  const float* ed = (const float*)d_in[4];
  const float* sg = (const float*)d_in[5];
  const float* su = (const float*)d_in[6];
  const float* sd = (const float*)d_in[7];
  float* out = (float*)d_out;

  char* ws = (char*)d_ws;
  size_t off = 0;
  auto take = [&](size_t sz) { size_t o = off; off += (sz + 255) & ~(size_t)255; return o; };
  const size_t OFF_XB   = take((size_t)NTOK * DIM * 2);
  const size_t OFF_WGT  = take((size_t)8 * HID * DIM * 2);
  const size_t OFF_WUT  = take((size_t)8 * HID * DIM * 2);
  const size_t OFF_WDT  = take((size_t)8 * HID * DIM * 2);
  const size_t OFF_SGT  = take((size_t)HID * DIM * 2);
  const size_t OFF_SUT  = take((size_t)HID * DIM * 2);
  const size_t OFF_SDT  = take((size_t)HID * DIM * 2);
  const size_t OFF_TI   = take((size_t)NTOK * 2 * 4);
  const size_t OFF_TW   = take((size_t)NTOK * 2 * 4);
  const size_t OFF_PERM = take((size_t)ROWS_CAP * 4);
  const size_t OFF_WROW = take((size_t)ROWS_CAP * 4);
  const size_t OFF_STATS= take(256);
  const size_t OFF_CURS = take(256);
  const size_t OFF_TE   = take(TCAP * 4);
  const size_t OFF_TR   = take(TCAP * 4);
  const size_t OFF_H    = off;   // h-buffer takes ALL remaining space

  const size_t TILE_H_BYTES = (size_t)128 * HID * 2;
  size_t avail = (ws_size > OFF_H) ? (ws_size - OFF_H) : 0;
  int G = (int)((avail / TILE_H_BYTES < (size_t)TCAP) ? (avail / TILE_H_BYTES) : (size_t)TCAP);
  if (G < 1) return;

  unsigned short* xb  = (unsigned short*)(ws + OFF_XB);
  unsigned short* WgT = (unsigned short*)(ws + OFF_WGT);
  unsigned short* WuT = (unsigned short*)(ws + OFF_WUT);
  unsigned short* WdT = (unsigned short*)(ws + OFF_WDT);
  unsigned short* SgT = (unsigned short*)(ws + OFF_SGT);
  unsigned short* SuT = (unsigned short*)(ws + OFF_SUT);
  unsigned short* SdT = (unsigned short*)(ws + OFF_SDT);
  int* top_idx        = (int*)(ws + OFF_TI);
  float* top_w        = (float*)(ws + OFF_TW);
  int* perm           = (int*)(ws + OFF_PERM);
  float* wrow         = (float*)(ws + OFF_WROW);
  int* counts         = (int*)(ws + OFF_STATS);
  float* f_cnt        = (float*)(ws + OFF_STATS + 32);
  float* P_sum        = (float*)(ws + OFF_STATS + 64);
  int* cursors        = (int*)(ws + OFF_CURS);
  int* tile_expert    = (int*)(ws + OFF_TE);
  int* tile_row0      = (int*)(ws + OFF_TR);
  unsigned short* hbuf = (unsigned short*)(ws + OFF_H);

  hipMemsetAsync(ws + OFF_STATS, 0, 256, stream);

  k_transpose_DH<<<dim3(HID / 32, DIM / 32, 18), dim3(32, 8), 0, stream>>>(
      eg, eu, sg, su, WgT, WuT, SgT, SuT);
  k_transpose_HD<<<dim3(DIM / 32, HID / 32, 9), dim3(32, 8), 0, stream>>>(
      ed, sd, WdT, SdT);

  k_router<<<256, 256, 0, stream>>>(x, gw, xb, top_idx, top_w, counts, f_cnt, P_sum);
  k_setup<<<1, 256, 0, stream>>>(counts, cursors, tile_expert, tile_row0, perm, wrow);
  k_scatter<<<NTOK * 2 / 256, 256, 0, stream>>>(top_idx, top_w, cursors, perm, wrow);

  for (int t0 = 0; t0 < TCAP; t0 += G) {
    int nt = (TCAP - t0 < G) ? (TCAP - t0) : G;
    int row_base = t0 * 128;
    k_stageA<<<dim3(HID / 64, nt), 256, 0, stream>>>(xb, WgT, WuT, SgT, SuT, perm,
                                                     tile_expert, tile_row0, hbuf, t0, row_base);
    int ns = 0;
    if (t0 < 64) { ns = 64 - t0; if (ns > nt) ns = nt; }
    int ne = nt - ns;
    if (ns > 0)
      k_stageB<true><<<dim3(DIM / 128, ns), 256, 0, stream>>>(hbuf, WdT, SdT, perm, wrow,
                                                              tile_expert, tile_row0, out, t0, row_base);
    if (ne > 0)
      k_stageB<false><<<dim3(DIM / 128, ne), 256, 0, stream>>>(hbuf, WdT, SdT, perm, wrow,
                                                               tile_expert, tile_row0, out, t0 + ns, row_base);
  }

  k_aux<<<1, 64, 0, stream>>>(f_cnt, P_sum, out + (size_t)NTOK * DIM);
}

// Round 13
// 922.837 us; speedup vs baseline: 1.0902x; 1.0472x over previous
//
#include <hip/hip_runtime.h>
#include <hip/hip_bf16.h>

#define NTOK 8192
#define DIM  1024
#define HID  2816
#define ROWS_CAP 25600   // 8192 shared + 16384 assignments + pad headroom
#define TCAP 200         // 64 shared tiles + max 135 expert tiles

typedef __bf16 bf16x8 __attribute__((ext_vector_type(8)));
typedef float  f32x4  __attribute__((ext_vector_type(4)));

__device__ __forceinline__ unsigned short f2bf(float f) {
  unsigned int x = __float_as_uint(f);
  unsigned int r = (x + 0x7fffu + ((x >> 16) & 1u)) >> 16;
  return (unsigned short)r;
}
__device__ __forceinline__ float gelu_erf(float g) {
  return 0.5f * g * (1.0f + erff(g * 0.70710678118654752f));
}

__device__ __forceinline__ void gload16(const void* g, void* l) {
  __builtin_amdgcn_global_load_lds(
      (__attribute__((address_space(1))) void*)(g),
      (__attribute__((address_space(3))) void*)(l), 16, 0, 0);
}

// ---- vectorized transpose: out[c][r] = bf16(in[r][c]), 64x64 tile ----
// loads float4 (16B/lane), writes ushort4 (8B/lane). R,C multiples of 64.
__device__ __forceinline__ void transpose64(const float* __restrict__ in,
                                            unsigned short* __restrict__ out,
                                            int R, int C) {
  __shared__ float t[64][65];
  int c0 = blockIdx.x * 64, r0 = blockIdx.y * 64;
  int tid = threadIdx.x;
  int lr = tid >> 4;            // 0..15
  int lc4 = (tid & 15) * 4;     // 0,4,...,60
  #pragma unroll
  for (int it = 0; it < 4; ++it) {
    int row = lr + it * 16;
    float4 v = *(const float4*)(in + (size_t)(r0 + row) * C + c0 + lc4);
    t[row][lc4] = v.x; t[row][lc4 + 1] = v.y;
    t[row][lc4 + 2] = v.z; t[row][lc4 + 3] = v.w;
  }
  __syncthreads();
  #pragma unroll
  for (int it = 0; it < 4; ++it) {
    int cloc = lr + it * 16;
    ushort4 w = make_ushort4(f2bf(t[lc4][cloc]), f2bf(t[lc4 + 1][cloc]),
                             f2bf(t[lc4 + 2][cloc]), f2bf(t[lc4 + 3][cloc]));
    *(ushort4*)(out + (size_t)(c0 + cloc) * R + r0 + lc4) = w;
  }
}

__global__ __launch_bounds__(256) void k_transpose_DH(
    const float* __restrict__ eg, const float* __restrict__ eu,
    const float* __restrict__ sg, const float* __restrict__ su,
    unsigned short* __restrict__ WgT, unsigned short* __restrict__ WuT,
    unsigned short* __restrict__ SgT, unsigned short* __restrict__ SuT) {
  int z = blockIdx.z;
  const float* in; unsigned short* out;
  if (z < 8)        { in = eg + (size_t)z * DIM * HID;       out = WgT + (size_t)z * DIM * HID; }
  else if (z < 16)  { in = eu + (size_t)(z - 8) * DIM * HID; out = WuT + (size_t)(z - 8) * DIM * HID; }
  else if (z == 16) { in = sg; out = SgT; }
  else              { in = su; out = SuT; }
  transpose64(in, out, DIM, HID);
}

__global__ __launch_bounds__(256) void k_transpose_HD(
    const float* __restrict__ ed, const float* __restrict__ sd,
    unsigned short* __restrict__ WdT, unsigned short* __restrict__ SdT) {
  int z = blockIdx.z;
  const float* in; unsigned short* out;
  if (z < 8) { in = ed + (size_t)z * HID * DIM; out = WdT + (size_t)z * HID * DIM; }
  else       { in = sd; out = SdT; }
  transpose64(in, out, HID, DIM);
}

// ---------------- router + fused x->bf16 cast (block-reduced stats) ----------------

__global__ __launch_bounds__(256) void k_router(const float* __restrict__ x,
                                                const float* __restrict__ gw,
                                                unsigned short* __restrict__ xb,
                                                int* __restrict__ top_idx,
                                                float* __restrict__ top_w,
                                                int* __restrict__ counts,
                                                float* __restrict__ f_cnt,
                                                float* __restrict__ P_sum) {
  __shared__ float s_p[8];
  __shared__ int   s_cnt[8];
  __shared__ int   s_f[8];
  int tid = threadIdx.x;
  if (tid < 8) { s_p[tid] = 0.f; s_cnt[tid] = 0; s_f[tid] = 0; }
  __syncthreads();

  int lane = tid & 63, wv = tid >> 6;
  float ploc[8] = {0,0,0,0,0,0,0,0};
  int   cloc[8] = {0,0,0,0,0,0,0,0};
  int   floc[8] = {0,0,0,0,0,0,0,0};

  for (int t = blockIdx.x * 4 + wv; t < NTOK; t += 2048) {
    const float4* xr = (const float4*)(x + (size_t)t * DIM) + lane * 4;
    float4 v0 = xr[0], v1 = xr[1], v2 = xr[2], v3 = xr[3];
    float xv[16] = {v0.x, v0.y, v0.z, v0.w, v1.x, v1.y, v1.z, v1.w,
                    v2.x, v2.y, v2.z, v2.w, v3.x, v3.y, v3.z, v3.w};
    ushort4* xw = (ushort4*)(xb + (size_t)t * DIM + lane * 16);
    #pragma unroll
    for (int q = 0; q < 4; ++q)
      xw[q] = make_ushort4(f2bf(xv[q * 4]), f2bf(xv[q * 4 + 1]),
                           f2bf(xv[q * 4 + 2]), f2bf(xv[q * 4 + 3]));
    float acc[8] = {0.f,0.f,0.f,0.f,0.f,0.f,0.f,0.f};
    #pragma unroll
    for (int i = 0; i < 16; ++i) {
      const float* g = gw + (size_t)(lane * 16 + i) * 8;
      #pragma unroll
      for (int e = 0; e < 8; ++e) acc[e] += xv[i] * g[e];
    }
    #pragma unroll
    for (int e = 0; e < 8; ++e) {
      #pragma unroll
      for (int off = 32; off > 0; off >>= 1)
        acc[e] += __shfl_xor(acc[e], off, 64);
    }
    if (lane == 0) {
      int i1 = 0; float l1 = acc[0];
      #pragma unroll
      for (int e = 1; e < 8; ++e) if (acc[e] > l1) { l1 = acc[e]; i1 = e; }
      int i2 = -1; float l2 = -3.0e38f;
      #pragma unroll
      for (int e = 0; e < 8; ++e) if (e != i1 && acc[e] > l2) { l2 = acc[e]; i2 = e; }
      float e2 = expf(l2 - l1);
      float inv12 = 1.0f / (1.0f + e2);
      top_idx[2 * t] = i1; top_idx[2 * t + 1] = i2;
      top_w[2 * t] = inv12; top_w[2 * t + 1] = e2 * inv12;
      float s = 0.f, p[8];
      #pragma unroll
      for (int e = 0; e < 8; ++e) { p[e] = expf(acc[e] - l1); s += p[e]; }
      float invs = 1.0f / s;
      #pragma unroll
      for (int e = 0; e < 8; ++e) {
        ploc[e] += p[e] * invs;
        cloc[e] += (e == i1) + (e == i2);
        floc[e] += (e == i1);
      }
    }
  }
  if (lane == 0) {
    #pragma unroll
    for (int e = 0; e < 8; ++e) {
      atomicAdd(&s_p[e], ploc[e]);
      atomicAdd(&s_cnt[e], cloc[e]);
      atomicAdd(&s_f[e], floc[e]);
    }
  }
  __syncthreads();
  if (tid < 8) {
    atomicAdd(&P_sum[tid], s_p[tid]);
    atomicAdd(&counts[tid], s_cnt[tid]);
    atomicAdd(&f_cnt[tid], (float)s_f[tid]);
  }
}

// ---------------- segment setup / scatter ----------------

__global__ __launch_bounds__(256) void k_setup(const int* __restrict__ counts,
                                               int* __restrict__ cursors,
                                               int* __restrict__ tile_expert,
                                               int* __restrict__ tile_row0,
                                               int* __restrict__ perm,
                                               float* __restrict__ wrow) {
  int t = threadIdx.x;
  for (int r = t; r < ROWS_CAP; r += 256) {
    perm[r] = (r < NTOK) ? r : 0;
    wrow[r] = (r < NTOK) ? 1.0f : 0.0f;
  }
  if (t == 0) {
    int so[8], pe[8];
    int cur = NTOK;
    for (int e = 0; e < 8; ++e) {
      so[e] = cur;
      pe[e] = ((counts[e] + 127) >> 7) << 7;
      cur += pe[e];
    }
    for (int e = 0; e < 8; ++e) cursors[e] = so[e];
    for (int tile = 0; tile < TCAP; ++tile) {
      int r0 = tile << 7;
      int ex;
      if (tile < NTOK / 128) ex = 8;            // shared expert
      else if (r0 < cur) {
        ex = 0;
        for (int e = 0; e < 8; ++e) if (r0 >= so[e] && r0 < so[e] + pe[e]) ex = e;
      } else ex = -1;
      tile_expert[tile] = ex;
      tile_row0[tile] = r0;
    }
  }
}

__global__ __launch_bounds__(256) void k_scatter(const int* __restrict__ top_idx,
                                                 const float* __restrict__ top_w,
                                                 int* __restrict__ cursors,
                                                 int* __restrict__ perm,
                                                 float* __restrict__ wrow) {
  int i = blockIdx.x * 256 + threadIdx.x;
  if (i < NTOK * 2) {
    int e = top_idx[i];
    float w = top_w[i];
    int slot = atomicAdd(&cursors[e], 1);
    perm[slot] = i >> 1;
    wrow[slot] = w;
  }
}

// ---------------- stage A: h = gelu(x@gate) * (x@up) -------------------------
// dbuf LDS + COUNTED vmcnt(6): previous tile's loads awaited, current tile's
// 6 loads stay in flight across the whole compute phase (T4, m218).

__global__ __launch_bounds__(256) void k_stageA(const unsigned short* __restrict__ xb,
    const unsigned short* __restrict__ WgT, const unsigned short* __restrict__ WuT,
    const unsigned short* __restrict__ SgT, const unsigned short* __restrict__ SuT,
    const int* __restrict__ perm,
    const int* __restrict__ tile_expert, const int* __restrict__ tile_row0,
    unsigned short* __restrict__ h, int t0, int row_base) {
  int tile = t0 + blockIdx.y;
  int e = tile_expert[tile];
  if (e < 0) return;
  const unsigned short* Bg = (e < 8) ? WgT + (size_t)e * HID * DIM : SgT;
  const unsigned short* Bu = (e < 8) ? WuT + (size_t)e * HID * DIM : SuT;
  int rows0 = tile_row0[tile];
  int h0 = blockIdx.x * 64;

  __shared__ unsigned short As[2][128 * 64];
  __shared__ unsigned short Bgs[2][64 * 64];
  __shared__ unsigned short Bus[2][64 * 64];

  int tid = threadIdx.x, lane = tid & 63, wv = tid >> 6;
  int wr = wv >> 1, wc = wv & 1;
  int rlo = lane >> 3;
  int koff = (((lane & 7) ^ rlo) * 8);       // pre-swizzled source column
  int rsw = (lane & 7) << 4;                 // read-side XOR (row&7)<<4

  int prow[4];
  #pragma unroll
  for (int i = 0; i < 4; ++i) prow[i] = perm[rows0 + i * 32 + wv * 8 + rlo];
  int bn[2];
  #pragma unroll
  for (int i = 0; i < 2; ++i) bn[i] = h0 + i * 32 + wv * 8 + rlo;

  f32x4 accg[4][2] = {};
  f32x4 accu[4][2] = {};

  auto stage = [&](int b, int k0) {
    #pragma unroll
    for (int i = 0; i < 4; ++i)
      gload16(xb + (size_t)prow[i] * DIM + k0 + koff, (char*)As[b] + (i * 32 + wv * 8) * 128);
    #pragma unroll
    for (int i = 0; i < 2; ++i) {
      gload16(Bg + (size_t)bn[i] * DIM + k0 + koff, (char*)Bgs[b] + (i * 32 + wv * 8) * 128);
      gload16(Bu + (size_t)bn[i] * DIM + k0 + koff, (char*)Bus[b] + (i * 32 + wv * 8) * 128);
    }
  };

  auto compute = [&](int b) {
    #pragma unroll
    for (int kk = 0; kk < 2; ++kk) {
      int kbyte = (kk * 64 + (lane >> 4) * 16) ^ rsw;
      bf16x8 a[4], bg[2], bu[2];
      #pragma unroll
      for (int mi = 0; mi < 4; ++mi)
        a[mi] = *(const bf16x8*)((const char*)As[b] + (wr * 64 + mi * 16 + (lane & 15)) * 128 + kbyte);
      #pragma unroll
      for (int ni = 0; ni < 2; ++ni) {
        bg[ni] = *(const bf16x8*)((const char*)Bgs[b] + (wc * 32 + ni * 16 + (lane & 15)) * 128 + kbyte);
        bu[ni] = *(const bf16x8*)((const char*)Bus[b] + (wc * 32 + ni * 16 + (lane & 15)) * 128 + kbyte);
      }
      #pragma unroll
      for (int mi = 0; mi < 4; ++mi) {
        #pragma unroll
        for (int ni = 0; ni < 2; ++ni) {
          accg[mi][ni] = __builtin_amdgcn_mfma_f32_16x16x32_bf16(a[mi], bg[ni], accg[mi][ni], 0, 0, 0);
          accu[mi][ni] = __builtin_amdgcn_mfma_f32_16x16x32_bf16(a[mi], bu[ni], accu[mi][ni], 0, 0, 0);
        }
      }
    }
  };

  stage(0, 0);
  int cur = 0;
  for (int kb = 0; kb < DIM / 64 - 1; ++kb) {
    stage(cur ^ 1, (kb + 1) * 64);
    __builtin_amdgcn_sched_barrier(0);
    asm volatile("s_waitcnt vmcnt(6)" ::: "memory");   // oldest 6 (buf[cur]) done
    __builtin_amdgcn_s_barrier();
    __builtin_amdgcn_sched_barrier(0);
    __builtin_amdgcn_s_setprio(1);
    compute(cur);
    __builtin_amdgcn_s_setprio(0);
    __builtin_amdgcn_s_barrier();                      // WAR: reads done before next overwrite
    cur ^= 1;
  }
  asm volatile("s_waitcnt vmcnt(0)" ::: "memory");
  __builtin_amdgcn_s_barrier();
  __builtin_amdgcn_sched_barrier(0);
  compute(cur);

  #pragma unroll
  for (int mi = 0; mi < 4; ++mi) {
    #pragma unroll
    for (int ni = 0; ni < 2; ++ni) {
      #pragma unroll
      for (int j = 0; j < 4; ++j) {
        int rg = rows0 - row_base + wr * 64 + mi * 16 + (lane >> 4) * 4 + j;
        int cg = h0 + wc * 32 + ni * 16 + (lane & 15);
        float g = accg[mi][ni][j];
        float u = accu[mi][ni][j];
        h[(size_t)rg * HID + cg] = f2bf(gelu_erf(g) * u);
      }
    }
  }
}

// ---------------- stage B: out(f32) = / += w * (h @ downT) ----------------

template <bool STORE>
__global__ __launch_bounds__(256) void k_stageB(const unsigned short* __restrict__ h,
    const unsigned short* __restrict__ WdT, const unsigned short* __restrict__ SdT,
    const int* __restrict__ perm, const float* __restrict__ wrow,
    const int* __restrict__ tile_expert, const int* __restrict__ tile_row0,
    float* __restrict__ out, int t0, int row_base) {
  int tile = t0 + blockIdx.y;
  int e = tile_expert[tile];
  if (e < 0) return;
  const unsigned short* Bd = (e < 8) ? WdT + (size_t)e * DIM * HID : SdT;
  int rows0 = tile_row0[tile];
  int n0 = blockIdx.x * 128;

  __shared__ unsigned short As[2][128 * 64];
  __shared__ unsigned short Bs[2][128 * 64];

  int tid = threadIdx.x, lane = tid & 63, wv = tid >> 6;
  int wr = wv >> 1, wc = wv & 1;
  int rlo = lane >> 3;
  int koff = (((lane & 7) ^ rlo) * 8);
  int rsw = (lane & 7) << 4;

  f32x4 acc[4][4] = {};

  auto stage = [&](int b, int k0) {
    #pragma unroll
    for (int i = 0; i < 4; ++i) {
      int rb = i * 32 + wv * 8;
      int r = rb + rlo;
      gload16(h + (size_t)(rows0 - row_base + r) * HID + k0 + koff, (char*)As[b] + rb * 128);
      gload16(Bd + (size_t)(n0 + r) * HID + k0 + koff, (char*)Bs[b] + rb * 128);
    }
  };

  auto compute = [&](int b) {
    #pragma unroll
    for (int kk = 0; kk < 2; ++kk) {
      int kbyte = (kk * 64 + (lane >> 4) * 16) ^ rsw;
      bf16x8 a[4], bb[4];
      #pragma unroll
      for (int mi = 0; mi < 4; ++mi)
        a[mi] = *(const bf16x8*)((const char*)As[b] + (wr * 64 + mi * 16 + (lane & 15)) * 128 + kbyte);
      #pragma unroll
      for (int ni = 0; ni < 4; ++ni)
        bb[ni] = *(const bf16x8*)((const char*)Bs[b] + (wc * 64 + ni * 16 + (lane & 15)) * 128 + kbyte);
      #pragma unroll
      for (int mi = 0; mi < 4; ++mi) {
        #pragma unroll
        for (int ni = 0; ni < 4; ++ni)
          acc[mi][ni] = __builtin_amdgcn_mfma_f32_16x16x32_bf16(a[mi], bb[ni], acc[mi][ni], 0, 0, 0);
      }
    }
  };

  stage(0, 0);
  int cur = 0;
  for (int kb = 0; kb < HID / 64 - 1; ++kb) {
    stage(cur ^ 1, (kb + 1) * 64);
    __builtin_amdgcn_sched_barrier(0);
    asm volatile("s_waitcnt vmcnt(8)" ::: "memory");   // oldest 8 (buf[cur]) done
    __builtin_amdgcn_s_barrier();
    __builtin_amdgcn_sched_barrier(0);
    __builtin_amdgcn_s_setprio(1);
    compute(cur);
    __builtin_amdgcn_s_setprio(0);
    __builtin_amdgcn_s_barrier();
    cur ^= 1;
  }
  asm volatile("s_waitcnt vmcnt(0)" ::: "memory");
  __builtin_amdgcn_s_barrier();
  __builtin_amdgcn_sched_barrier(0);
  compute(cur);

  #pragma unroll
  for (int mi = 0; mi < 4; ++mi) {
    #pragma unroll
    for (int j = 0; j < 4; ++j) {
      int rl = wr * 64 + mi * 16 + (lane >> 4) * 4 + j;
      int token = perm[rows0 + rl];
      float w = wrow[rows0 + rl];
      #pragma unroll
      for (int ni = 0; ni < 4; ++ni) {
        int col = n0 + wc * 64 + ni * 16 + (lane & 15);
        if (STORE) out[(size_t)token * DIM + col] = w * acc[mi][ni][j];
        else atomicAdd(&out[(size_t)token * DIM + col], w * acc[mi][ni][j]);
      }
    }
  }
}

// ---------------- aux loss (f32) ----------------

__global__ void k_aux(const float* __restrict__ f_cnt, const float* __restrict__ P_sum,
                      float* __restrict__ aux_out) {
  if (threadIdx.x == 0 && blockIdx.x == 0) {
    float a = 0.f;
    #pragma unroll
    for (int e = 0; e < 8; ++e) a += f_cnt[e] * P_sum[e];
    a *= 0.01f * 8.f / ((float)NTOK * (float)NTOK);
    aux_out[0] = a;
  }
}

// ---------------- launch ----------------

extern "C" void kernel_launch(void* const* d_in, const int* in_sizes, int n_in,
                              void* d_out, int out_size, void* d_ws, size_t ws_size,
                              hipStream_t stream) {
  const float* x  = (const float*)d_in[0];
  const float* gw = (const float*)d_in[1];
  const float* eg = (const float*)d_in[2];
  const float* eu = (const float*)d_in[3];
  const float* ed = (const float*)d_in[4];
  const float* sg = (const float*)d_in[5];
  const float* su = (const float*)d_in[6];
  const float* sd = (const float*)d_in[7];
  float* out = (float*)d_out;

  char* ws = (char*)d_ws;
  size_t off = 0;
  auto take = [&](size_t sz) { size_t o = off; off += (sz + 255) & ~(size_t)255; return o; };
  const size_t OFF_XB   = take((size_t)NTOK * DIM * 2);
  const size_t OFF_WGT  = take((size_t)8 * HID * DIM * 2);
  const size_t OFF_WUT  = take((size_t)8 * HID * DIM * 2);
  const size_t OFF_WDT  = take((size_t)8 * HID * DIM * 2);
  const size_t OFF_SGT  = take((size_t)HID * DIM * 2);
  const size_t OFF_SUT  = take((size_t)HID * DIM * 2);
  const size_t OFF_SDT  = take((size_t)HID * DIM * 2);
  const size_t OFF_TI   = take((size_t)NTOK * 2 * 4);
  const size_t OFF_TW   = take((size_t)NTOK * 2 * 4);
  const size_t OFF_PERM = take((size_t)ROWS_CAP * 4);
  const size_t OFF_WROW = take((size_t)ROWS_CAP * 4);
  const size_t OFF_STATS= take(256);
  const size_t OFF_CURS = take(256);
  const size_t OFF_TE   = take(TCAP * 4);
  const size_t OFF_TR   = take(TCAP * 4);
  const size_t OFF_H    = off;   // h-buffer takes ALL remaining space

  const size_t TILE_H_BYTES = (size_t)128 * HID * 2;
  size_t avail = (ws_size > OFF_H) ? (ws_size - OFF_H) : 0;
  int G = (int)((avail / TILE_H_BYTES < (size_t)TCAP) ? (avail / TILE_H_BYTES) : (size_t)TCAP);
  if (G < 1) return;

  unsigned short* xb  = (unsigned short*)(ws + OFF_XB);
  unsigned short* WgT = (unsigned short*)(ws + OFF_WGT);
  unsigned short* WuT = (unsigned short*)(ws + OFF_WUT);
  unsigned short* WdT = (unsigned short*)(ws + OFF_WDT);
  unsigned short* SgT = (unsigned short*)(ws + OFF_SGT);
  unsigned short* SuT = (unsigned short*)(ws + OFF_SUT);
  unsigned short* SdT = (unsigned short*)(ws + OFF_SDT);
  int* top_idx        = (int*)(ws + OFF_TI);
  float* top_w        = (float*)(ws + OFF_TW);
  int* perm           = (int*)(ws + OFF_PERM);
  float* wrow         = (float*)(ws + OFF_WROW);
  int* counts         = (int*)(ws + OFF_STATS);
  float* f_cnt        = (float*)(ws + OFF_STATS + 32);
  float* P_sum        = (float*)(ws + OFF_STATS + 64);
  int* cursors        = (int*)(ws + OFF_CURS);
  int* tile_expert    = (int*)(ws + OFF_TE);
  int* tile_row0      = (int*)(ws + OFF_TR);
  unsigned short* hbuf = (unsigned short*)(ws + OFF_H);

  hipMemsetAsync(ws + OFF_STATS, 0, 256, stream);

  k_transpose_DH<<<dim3(HID / 64, DIM / 64, 18), 256, 0, stream>>>(
      eg, eu, sg, su, WgT, WuT, SgT, SuT);
  k_transpose_HD<<<dim3(DIM / 64, HID / 64, 9), 256, 0, stream>>>(
      ed, sd, WdT, SdT);

  k_router<<<512, 256, 0, stream>>>(x, gw, xb, top_idx, top_w, counts, f_cnt, P_sum);
  k_setup<<<1, 256, 0, stream>>>(counts, cursors, tile_expert, tile_row0, perm, wrow);
  k_scatter<<<NTOK * 2 / 256, 256, 0, stream>>>(top_idx, top_w, cursors, perm, wrow);

  for (int t0 = 0; t0 < TCAP; t0 += G) {
    int nt = (TCAP - t0 < G) ? (TCAP - t0) : G;
    int row_base = t0 * 128;
    k_stageA<<<dim3(HID / 64, nt), 256, 0, stream>>>(xb, WgT, WuT, SgT, SuT, perm,
                                                     tile_expert, tile_row0, hbuf, t0, row_base);
    int ns = 0;
    if (t0 < 64) { ns = 64 - t0; if (ns > nt) ns = nt; }
    int ne = nt - ns;
    if (ns > 0)
      k_stageB<true><<<dim3(DIM / 128, ns), 256, 0, stream>>>(hbuf, WdT, SdT, perm, wrow,
                                                              tile_expert, tile_row0, out, t0, row_base);
    if (ne > 0)
      k_stageB<false><<<dim3(DIM / 128, ne), 256, 0, stream>>>(hbuf, WdT, SdT, perm, wrow,
                                                               tile_expert, tile_row0, out, t0 + ns, row_base);
  }

  k_aux<<<1, 64, 0, stream>>>(f_cnt, P_sum, out + (size_t)NTOK * DIM);
}